// Round 13
// baseline (234.393 us; speedup 1.0000x reference)
//
#include <hip/hip_runtime.h>
#include <hip/hip_bf16.h>

#define N_NODES 30000
#define F_INLEN 500
#define HID 16
#define OUTC 3
#define NEDGE 960000
#define YPITCH 20               // shorts per row: 40B -> conflict-free, 8B aligned
#define NBIN 938                // bins of 32 nodes: 938*32 = 30016 >= 30000
#define HBLK 128                // hist/reorder blocks (R10/R12-proven)
#define EPRH (NEDGE / HBLK)     // 7500 edges per hist/reorder block
#define ECAP 1536               // per-bin edge capacity (mean 1024, max ~1180)
#define NPB2 235                // dinv/h0-scale nodes per reorder block: 128*235 = 30080

typedef float  f32x4 __attribute__((ext_vector_type(4)));
typedef float  f32x2 __attribute__((ext_vector_type(2)));
typedef short  s16x8 __attribute__((ext_vector_type(8)));

static __device__ __forceinline__ unsigned short f2bf(float f) {
    unsigned int u = __float_as_uint(f);
    unsigned int r = (u + 0x7fffu + ((u >> 16) & 1u)) >> 16;
    return (unsigned short)r;
}
static __device__ __forceinline__ unsigned int pack_bf16x2(float v0, float v1) {
#if __has_builtin(__builtin_amdgcn_cvt_pk_bf16_f32)
    typedef __bf16 bf16x2_t __attribute__((ext_vector_type(2)));
    union { bf16x2_t v; unsigned int u; } cv;
    cv.v = __builtin_amdgcn_cvt_pk_bf16_f32(v0, v1);
    return cv.u;
#else
    return __builtin_amdgcn_perm(__float_as_uint(v1), __float_as_uint(v0), 0x07060302);
#endif
}

// ---------------- K0: B-fragments + zero degi --------------------------------
__global__ void setup_kernel(const float* __restrict__ w2, short* __restrict__ bfragsG,
                             int* __restrict__ degi)
{
    const int tid = threadIdx.x;
    const int gid = blockIdx.x * 256 + tid;
    if (gid < N_NODES) degi[gid] = 0;
    if (blockIdx.x == 0 && tid < 64) {
        const int n16 = tid & 15, q = tid >> 4;
#pragma unroll
        for (int j = 0; j < 8; j++) {
            {   // s = 0
                const int c = q * 8 + j;
                const int t = c >> 4, i = c & 15;
                bfragsG[tid * 16 + j] = (short)f2bf(w2[n16 * 48 + i * 3 + t]);
            }
            {   // s = 1 (zero for c >= 48)
                const int c = 32 + q * 8 + j;
                short v = 0;
                if (c < 48) { const int t = c >> 4, i = c & 15; v = (short)f2bf(w2[n16 * 48 + i * 3 + t]); }
                bfragsG[tid * 16 + 8 + j] = v;
            }
        }
    }
}

// ---------------- K1: [blocks 0..127] hist+degi  [128..30127] conv -----------
__global__ __launch_bounds__(256, 7) void conv_hist(
    const float* __restrict__ x,
    const float* __restrict__ w1, const float* __restrict__ b1,
    const float* __restrict__ b2, const short* __restrict__ bfragsG,
    const int* __restrict__ dst, int* __restrict__ degi,
    int* __restrict__ cntbase, float* __restrict__ h0)
{
    __shared__ __align__(16) float xp[502];
    __shared__ __align__(16) unsigned short yh[516 * YPITCH];
    __shared__ float red[64];

    const int tid = threadIdx.x;

    if (blockIdx.x < HBLK) {
        int* histH = (int*)yh;   // alias: 938 ints < yh size
        for (int i = tid; i < NBIN; i += 256) histH[i] = 0;
        __syncthreads();
        const int e0 = blockIdx.x * EPRH;
        for (int e = e0 + tid; e < e0 + EPRH; e += 256) {
            const int d = dst[e];
            atomicAdd(&histH[d >> 5], 1);
            atomicAdd(&degi[d], 1);
        }
        __syncthreads();
        for (int i = tid; i < NBIN; i += 256) cntbase[blockIdx.x * NBIN + i] = histH[i];
        return;
    }

    const int node = blockIdx.x - HBLK;
    const int lane = tid & 63;
    const int wave = tid >> 6;
    const int n16  = lane & 15;
    const int q    = lane >> 4;

    if (tid == 0) { xp[0] = 0.f; xp[501] = 0.f; }
    if (tid < 125) {
        const float4 v = ((const float4*)(x + (long long)node * F_INLEN))[tid];
        xp[4 * tid + 1] = v.x; xp[4 * tid + 2] = v.y;
        xp[4 * tid + 3] = v.z; xp[4 * tid + 4] = v.w;
    }
    {
        const int ri = tid >> 4;
        const int row = (ri == 0) ? 0 : (500 + ri);
        yh[row * YPITCH + (tid & 15)] = 0;
    }
    const s16x8* bfp = (const s16x8*)(bfragsG + lane * 16);
    const s16x8 bh0 = bfp[0], bh1 = bfp[1];

    f32x2 wt0[8], wt1[8], wt2[8], bb[8];
#pragma unroll
    for (int cp = 0; cp < 8; cp++) {
        const int c0 = 2 * cp, c1 = 2 * cp + 1;
        wt0[cp] = (f32x2){w1[c0 * 3 + 0], w1[c1 * 3 + 0]};
        wt1[cp] = (f32x2){w1[c0 * 3 + 1], w1[c1 * 3 + 1]};
        wt2[cp] = (f32x2){w1[c0 * 3 + 2], w1[c1 * 3 + 2]};
        bb[cp]  = (f32x2){b1[c0], b1[c1]};
    }
    __syncthreads();

    for (int p = tid; p < 500; p += 256) {
        const float x0 = xp[p], x1 = xp[p + 1], x2 = xp[p + 2];
        const f32x2 xv0 = {x0, x0}, xv1 = {x1, x1}, xv2 = {x2, x2};
        const f32x2 zero = {0.f, 0.f};
        unsigned int hp[8];
#pragma unroll
        for (int cp = 0; cp < 8; cp++) {
            f32x2 a = bb[cp];
            a = __builtin_elementwise_fma(wt0[cp], xv0, a);
            a = __builtin_elementwise_fma(wt1[cp], xv1, a);
            a = __builtin_elementwise_fma(wt2[cp], xv2, a);
            a = __builtin_elementwise_max(a, zero);
            hp[cp] = pack_bf16x2(a[0], a[1]);
        }
        uint2* d = (uint2*)&yh[(p + 1) * YPITCH];
        d[0] = make_uint2(hp[0], hp[1]);
        d[1] = make_uint2(hp[2], hp[3]);
        d[2] = make_uint2(hp[4], hp[5]);
        d[3] = make_uint2(hp[6], hp[7]);
    }
    __syncthreads();

    struct S8 { short4 lo, hi; };
    float mx0 = -3.0e38f, mx1 = -3.0e38f, mx2 = -3.0e38f, mx3 = -3.0e38f;
#pragma unroll
    for (int it = 0; it < 8; it++) {
        const int tile = wave * 8 + it;
        const int p0 = tile * 16 + n16;
        const int cA = (q & 1) * 8;
        const int rA = p0 + (q >> 1);
        const int rB = p0 + 2 + (q >> 1);
        S8 t0, t1;
        t0.lo = *(const short4*)&yh[rA * YPITCH + cA];
        t0.hi = *(const short4*)&yh[rA * YPITCH + cA + 4];
        t1.lo = *(const short4*)&yh[rB * YPITCH + cA];
        t1.hi = *(const short4*)&yh[rB * YPITCH + cA + 4];
        const s16x8 ah0 = *(const s16x8*)&t0;
        const s16x8 ah1 = *(const s16x8*)&t1;
        f32x4 acc = {0.f, 0.f, 0.f, 0.f};
        acc = __builtin_amdgcn_mfma_f32_16x16x32_bf16(ah0, bh0, acc, 0, 0, 0);
        acc = __builtin_amdgcn_mfma_f32_16x16x32_bf16(ah1, bh1, acc, 0, 0, 0);
        if (it < 7) {
            mx0 = fmaxf(mx0, acc[0]);
            mx1 = fmaxf(mx1, acc[1]);
            mx2 = fmaxf(mx2, acc[2]);
            mx3 = fmaxf(mx3, acc[3]);
        } else if (wave < 3) {
            mx0 = fmaxf(mx0, acc[0]);
            mx1 = fmaxf(mx1, acc[1]);
            mx2 = fmaxf(mx2, acc[2]);
            mx3 = fmaxf(mx3, acc[3]);
        } else if (q == 0) {
            mx0 = fmaxf(mx0, acc[0]);
            mx1 = fmaxf(mx1, acc[1]);
            mx2 = fmaxf(mx2, acc[2]);
            mx3 = fmaxf(mx3, acc[3]);
        }
    }
    float m = fmaxf(fmaxf(mx0, mx1), fmaxf(mx2, mx3));
    m = fmaxf(m, __shfl_xor(m, 16));
    m = fmaxf(m, __shfl_xor(m, 32));
    if (lane < 16) red[wave * 16 + lane] = m;
    __syncthreads();
    if (tid < 16) {
        const float mm = fmaxf(fmaxf(red[tid], red[16 + tid]), fmaxf(red[32 + tid], red[48 + tid]));
        h0[node * HID + tid] = fmaxf(mm + b2[tid], 0.f);
    }
}

// ---------------- K2: reorder (fused int2 scan) + dinv + h0 prescale ---------
// 128 blocks x 512 thr, 7500 edges each. srt packs src | (dst<<15) (30 bits).
__global__ __launch_bounds__(512) void reorder2(
    const int* __restrict__ src, const int* __restrict__ dst,
    const int* __restrict__ cntbase, int* __restrict__ packed,
    int* __restrict__ binstart, const int* __restrict__ degi,
    float* __restrict__ dinv, float* __restrict__ h0)
{
    __shared__ int2 sc2A[NBIN], sc2B[NBIN];
    __shared__ int gexc[NBIN];
    __shared__ int lexc[NBIN];
    __shared__ int cursor[NBIN];
    __shared__ int srt[EPRH];
    const int tid = threadIdx.x;
    const int blk = blockIdx.x;

    // A: per-bin reduce over blocks (coalesced column reads) + psum(<blk) + own
    for (int bin = tid; bin < NBIN; bin += 512) {
        int tot = 0, psum = 0, lc = 0;
        for (int k = 0; k < HBLK; k++) {
            const int c = cntbase[k * NBIN + bin];
            tot += c;
            if (k < blk) psum += c;
            if (k == blk) lc = c;
        }
        cursor[bin] = tot;           // temp: tot
        gexc[bin]   = psum;          // temp: psum(<blk)
        lexc[bin]   = lc;            // temp: own count
        sc2A[bin]   = make_int2(tot, lc);
    }
    __syncthreads();
    // fused inclusive scan over (tot, lc)
    {
        int2* pA = sc2A; int2* pB = sc2B;
        for (int off = 1; off < NBIN; off <<= 1) {
            for (int i = tid; i < NBIN; i += 512) {
                int2 v = pA[i];
                if (i >= off) { const int2 u = pA[i - off]; v.x += u.x; v.y += u.y; }
                pB[i] = v;
            }
            __syncthreads();
            int2* tp = pA; pA = pB; pB = tp;
        }
        for (int i = tid; i < NBIN; i += 512) {
            const int tot = cursor[i];
            const int lc  = lexc[i];
            const int et  = pA[i].x - tot;   // global binstart
            const int el  = pA[i].y - lc;    // local exclusive
            gexc[i] += et;
            if (blk == 0) binstart[i] = et;
            lexc[i]   = el;
            cursor[i] = el;
        }
        if (blk == 0 && tid == 0) binstart[NBIN] = NEDGE;
    }
    __syncthreads();
    // B: LDS counting-sort scatter (by bin)
    const int e0 = blk * EPRH;
    for (int e = e0 + tid; e < e0 + EPRH; e += 512) {
        const int d = dst[e];
        const int bin = d >> 5;
        const int pos = atomicAdd(&cursor[bin], 1);
        srt[pos] = src[e] | (d << 15);
    }
    __syncthreads();
    // C: bin-sorted writeout (runs of ~8 -> mostly coalesced)
    for (int i = tid; i < EPRH; i += 512) {
        const int bin = srt[i] >> 20;
        packed[gexc[bin] + (i - lexc[bin])] = srt[i];
    }
    // D: dinv + in-place h0 prescale for own node slice
    const int n0 = blk * NPB2;
    for (int n = n0 + tid; n < n0 + NPB2 && n < N_NODES; n += 512) {
        const float dv = rsqrtf((float)(degi[n] + 1));
        dinv[n] = dv;
        f32x4* h4 = (f32x4*)(h0 + n * HID);
#pragma unroll
        for (int k = 0; k < 4; k++) h4[k] = h4[k] * dv;
    }
}

// ---------------- K3: agg layer 1 (h0 prescaled) + W1 + relu + W2 ------------
// t2p4[node] = (t2p.x, t2p.y, t2p.z, dv) -- dv carried for agg2
__global__ __launch_bounds__(256) void agg1_kernel(
    const int* __restrict__ binstart, const int* __restrict__ packed,
    const float* __restrict__ h0,
    const float* __restrict__ W1, const float* __restrict__ b1g,
    const float* __restrict__ W2, float4* __restrict__ t2p4)
{
    __shared__ float w1s[256];
    __shared__ float w2s[48];
    __shared__ float b1s[16];
    __shared__ float accS[32 * 17];
    __shared__ int eL[ECAP];
    __shared__ int srt[ECAP];
    __shared__ int h32[32], ls32[32], lofs32[32];
    const int tid = threadIdx.x;
    const int blk = blockIdx.x;
    w1s[tid] = W1[tid];
    if (tid < 48) w2s[tid] = W2[tid];
    if (tid < 16) b1s[tid] = b1g[tid];
    if (tid < 32) h32[tid] = 0;
    const int beg = binstart[blk];
    const int cnt = binstart[blk + 1] - beg;
    __syncthreads();
    for (int j = tid; j < cnt; j += 256) {
        const int p = packed[beg + j];
        eL[j] = p;
        atomicAdd(&h32[(p >> 15) & 31], 1);
    }
    __syncthreads();
    if (tid < 32) {
        const int v = h32[tid];
        int inc = v;
#pragma unroll
        for (int off = 1; off < 32; off <<= 1) {
            const int y = __shfl_up(inc, off);
            if (tid >= off) inc += y;
        }
        ls32[tid] = inc - v;
        lofs32[tid] = inc - v;
    }
    __syncthreads();
    for (int j = tid; j < cnt; j += 256) {
        const int p = eL[j];
        const int pos = atomicAdd(&lofs32[(p >> 15) & 31], 1);
        srt[pos] = p;
    }
    __syncthreads();
    const int n = tid >> 3;
    const int eslot = (tid >> 2) & 1;
    const int q = tid & 3;
    const int node = blk * 32 + n;
    const bool valid = node < N_NODES;
    f32x4 acc = {0.f, 0.f, 0.f, 0.f};
    if (valid) {
        const int s0 = ls32[n];
        const int s1 = s0 + h32[n];
        for (int i = s0 + eslot; i < s1; i += 2) {
            const int s = srt[i] & 32767;
            acc += *(const f32x4*)(h0 + s * HID + q * 4);
        }
    }
#pragma unroll
    for (int c = 0; c < 4; c++) acc[c] += __shfl_xor(acc[c], 4);
    if (valid && eslot == 0) {
        acc += *(const f32x4*)(h0 + node * HID + q * 4);   // self (prescaled)
        accS[n * 17 + q * 4 + 0] = acc[0];
        accS[n * 17 + q * 4 + 1] = acc[1];
        accS[n * 17 + q * 4 + 2] = acc[2];
        accS[n * 17 + q * 4 + 3] = acc[3];
    }
    __syncthreads();
    if (tid < 128) {
        const int n2 = tid >> 2;
        const int node2 = blk * 32 + n2;
        if (node2 < N_NODES) {
            const float dv = rsqrtf((float)(h32[n2] + 1));   // degree from local hist
            const int q2 = tid & 3;
            float y0 = 0.f, y1 = 0.f, y2 = 0.f, y3 = 0.f;
#pragma unroll
            for (int i = 0; i < 16; i++) {
                const float a = accS[n2 * 17 + i];
                y0 = fmaf(a, w1s[i * 16 + q2 * 4 + 0], y0);
                y1 = fmaf(a, w1s[i * 16 + q2 * 4 + 1], y1);
                y2 = fmaf(a, w1s[i * 16 + q2 * 4 + 2], y2);
                y3 = fmaf(a, w1s[i * 16 + q2 * 4 + 3], y3);
            }
            float d0 = 0.f, d1 = 0.f, d2 = 0.f;
            const float yv[4] = {y0, y1, y2, y3};
#pragma unroll
            for (int j = 0; j < 4; j++) {
                const int o = q2 * 4 + j;
                const float h = fmaxf(b1s[o] + dv * yv[j], 0.f);
                d0 = fmaf(h, w2s[o * 3 + 0], d0);
                d1 = fmaf(h, w2s[o * 3 + 1], d1);
                d2 = fmaf(h, w2s[o * 3 + 2], d2);
            }
            d0 += __shfl_xor(d0, 1); d0 += __shfl_xor(d0, 2);
            d1 += __shfl_xor(d1, 1); d1 += __shfl_xor(d1, 2);
            d2 += __shfl_xor(d2, 1); d2 += __shfl_xor(d2, 2);
            if (q2 == 0) t2p4[node2] = make_float4(d0 * dv, d1 * dv, d2 * dv, dv);
        }
    }
}

// ---------------- K4: agg layer 2 (sortless) + bias + log_softmax ------------
// direct LDS accumulation, 3 atomics/edge; dv from t2p4[node].w
__global__ __launch_bounds__(256) void agg2_kernel(
    const int* __restrict__ binstart, const int* __restrict__ packed,
    const float4* __restrict__ t2p4,
    const float* __restrict__ b2g, float* __restrict__ out)
{
    __shared__ float acc2[32 * 5];
    const int tid = threadIdx.x;
    const int blk = blockIdx.x;
    for (int i = tid; i < 32 * 5; i += 256) acc2[i] = 0.f;
    const int beg = binstart[blk];
    const int end = binstart[blk + 1];
    __syncthreads();
    for (int j = beg + tid; j < end; j += 256) {
        const int p = packed[j];
        const int s = p & 32767;
        const int dl = (p >> 15) & 31;
        const float4 v = t2p4[s];
        atomicAdd(&acc2[dl * 5 + 0], v.x);
        atomicAdd(&acc2[dl * 5 + 1], v.y);
        atomicAdd(&acc2[dl * 5 + 2], v.z);
    }
    __syncthreads();
    if (tid < 32) {
        const int node = blk * 32 + tid;
        if (node < N_NODES) {
            const float4 self = t2p4[node];
            const float dv = self.w;
            const float z0 = b2g[0] + dv * (acc2[tid * 5 + 0] + self.x);
            const float z1 = b2g[1] + dv * (acc2[tid * 5 + 1] + self.y);
            const float z2 = b2g[2] + dv * (acc2[tid * 5 + 2] + self.z);
            const float m = fmaxf(z0, fmaxf(z1, z2));
            const float lg = m + logf(expf(z0 - m) + expf(z1 - m) + expf(z2 - m));
            out[node * 3 + 0] = z0 - lg;
            out[node * 3 + 1] = z1 - lg;
            out[node * 3 + 2] = z2 - lg;
        }
    }
}

extern "C" void kernel_launch(void* const* d_in, const int* in_sizes, int n_in,
                              void* d_out, int out_size, void* d_ws, size_t ws_size,
                              hipStream_t stream)
{
    const float* x   = (const float*)d_in[0];
    const float* w1  = (const float*)d_in[1];
    const float* b1  = (const float*)d_in[2];
    const float* w2  = (const float*)d_in[3];
    const float* b2  = (const float*)d_in[4];
    const float* g1w = (const float*)d_in[5];
    const float* g1b = (const float*)d_in[6];
    const float* g2w = (const float*)d_in[7];
    const float* g2b = (const float*)d_in[8];
    const int*   ei  = (const int*)d_in[9];
    const int* src = ei;
    const int* dst = ei + NEDGE;

    float* ws = (float*)d_ws;
    float*  h0      = ws;                       // 480000 f (prescaled in place)
    float*  dinv    = ws + 480000;              // 30000 f
    float4* t2p4    = (float4*)(ws + 510000);   // 30000 float4 (16B aligned)
    int*    degi    = (int*)(ws + 630000);      // 30000 i
    int*    cntbase = (int*)(ws + 660000);      // 128*938 = 120064 i (blk-major)
    int*    binstart= (int*)(ws + 780064);      // 939 (+pad)
    int*    packed  = (int*)(ws + 781024);      // 960000 i
    short*  bfragsG = (short*)(ws + 1741024);   // 1024 s
    float*  out     = (float*)d_out;

    setup_kernel<<<118, 256, 0, stream>>>(w2, bfragsG, degi);
    conv_hist<<<HBLK + N_NODES, 256, 0, stream>>>(x, w1, b1, b2, bfragsG,
                                                  dst, degi, cntbase, h0);
    reorder2<<<HBLK, 512, 0, stream>>>(src, dst, cntbase, packed, binstart,
                                       degi, dinv, h0);
    agg1_kernel<<<NBIN, 256, 0, stream>>>(binstart, packed, h0,
                                          g1w, g1b, g2w, t2p4);
    agg2_kernel<<<NBIN, 256, 0, stream>>>(binstart, packed, t2p4, g2b, out);
}

// Round 14
// 229.517 us; speedup vs baseline: 1.0212x; 1.0212x over previous
//
#include <hip/hip_runtime.h>
#include <hip/hip_bf16.h>

#define N_NODES 30000
#define F_INLEN 500
#define HID 16
#define OUTC 3
#define NEDGE 960000
#define YPITCH 20               // shorts per row: 40B -> conflict-free, 8B aligned
#define NBIN 938                // bins of 32 nodes: 938*32 = 30016 >= 30000
#define HBLK 128                // hist/reorder blocks (R10/R12-proven)
#define EPRH (NEDGE / HBLK)     // 7500 edges per hist/reorder block
#define ECAP 1536               // per-bin edge capacity (mean 1024, max ~1180)
#define NPB2 235                // dinv/h0-scale nodes per reorder block: 128*235 = 30080

typedef float  f32x4 __attribute__((ext_vector_type(4)));
typedef float  f32x2 __attribute__((ext_vector_type(2)));
typedef short  s16x8 __attribute__((ext_vector_type(8)));

static __device__ __forceinline__ unsigned short f2bf(float f) {
    unsigned int u = __float_as_uint(f);
    unsigned int r = (u + 0x7fffu + ((u >> 16) & 1u)) >> 16;
    return (unsigned short)r;
}
static __device__ __forceinline__ unsigned int pack_bf16x2(float v0, float v1) {
#if __has_builtin(__builtin_amdgcn_cvt_pk_bf16_f32)
    typedef __bf16 bf16x2_t __attribute__((ext_vector_type(2)));
    union { bf16x2_t v; unsigned int u; } cv;
    cv.v = __builtin_amdgcn_cvt_pk_bf16_f32(v0, v1);
    return cv.u;
#else
    return __builtin_amdgcn_perm(__float_as_uint(v1), __float_as_uint(v0), 0x07060302);
#endif
}

// ---------------- K0: B-fragments only (degi zeroed by memset) ---------------
__global__ void setup_kernel(const float* __restrict__ w2, short* __restrict__ bfragsG)
{
    const int tid = threadIdx.x;   // 64 threads
    const int n16 = tid & 15, q = tid >> 4;
#pragma unroll
    for (int j = 0; j < 8; j++) {
        {   // s = 0
            const int c = q * 8 + j;
            const int t = c >> 4, i = c & 15;
            bfragsG[tid * 16 + j] = (short)f2bf(w2[n16 * 48 + i * 3 + t]);
        }
        {   // s = 1 (zero for c >= 48)
            const int c = 32 + q * 8 + j;
            short v = 0;
            if (c < 48) { const int t = c >> 4, i = c & 15; v = (short)f2bf(w2[n16 * 48 + i * 3 + t]); }
            bfragsG[tid * 16 + 8 + j] = v;
        }
    }
}

// ---------------- K1: [blocks 0..127] hist+degi  [128..30127] conv -----------
__global__ __launch_bounds__(256, 7) void conv_hist(
    const float* __restrict__ x,
    const float* __restrict__ w1, const float* __restrict__ b1,
    const float* __restrict__ b2, const short* __restrict__ bfragsG,
    const int* __restrict__ dst, int* __restrict__ degi,
    int* __restrict__ cntbase, float* __restrict__ h0)
{
    __shared__ __align__(16) float xp[502];
    __shared__ __align__(16) unsigned short yh[516 * YPITCH];
    __shared__ float red[64];

    const int tid = threadIdx.x;

    if (blockIdx.x < HBLK) {
        int* histH = (int*)yh;   // alias: 938 ints < yh size
        for (int i = tid; i < NBIN; i += 256) histH[i] = 0;
        __syncthreads();
        const int e0 = blockIdx.x * EPRH;
        for (int e = e0 + tid; e < e0 + EPRH; e += 256) {
            const int d = dst[e];
            atomicAdd(&histH[d >> 5], 1);
            atomicAdd(&degi[d], 1);
        }
        __syncthreads();
        for (int i = tid; i < NBIN; i += 256) cntbase[blockIdx.x * NBIN + i] = histH[i];
        return;
    }

    const int node = blockIdx.x - HBLK;
    const int lane = tid & 63;
    const int wave = tid >> 6;
    const int n16  = lane & 15;
    const int q    = lane >> 4;

    if (tid == 0) { xp[0] = 0.f; xp[501] = 0.f; }
    if (tid < 125) {
        const float4 v = ((const float4*)(x + (long long)node * F_INLEN))[tid];
        xp[4 * tid + 1] = v.x; xp[4 * tid + 2] = v.y;
        xp[4 * tid + 3] = v.z; xp[4 * tid + 4] = v.w;
    }
    {
        const int ri = tid >> 4;
        const int row = (ri == 0) ? 0 : (500 + ri);
        yh[row * YPITCH + (tid & 15)] = 0;
    }
    const s16x8* bfp = (const s16x8*)(bfragsG + lane * 16);
    const s16x8 bh0 = bfp[0], bh1 = bfp[1];

    f32x2 wt0[8], wt1[8], wt2[8], bb[8];
#pragma unroll
    for (int cp = 0; cp < 8; cp++) {
        const int c0 = 2 * cp, c1 = 2 * cp + 1;
        wt0[cp] = (f32x2){w1[c0 * 3 + 0], w1[c1 * 3 + 0]};
        wt1[cp] = (f32x2){w1[c0 * 3 + 1], w1[c1 * 3 + 1]};
        wt2[cp] = (f32x2){w1[c0 * 3 + 2], w1[c1 * 3 + 2]};
        bb[cp]  = (f32x2){b1[c0], b1[c1]};
    }
    __syncthreads();

    for (int p = tid; p < 500; p += 256) {
        const float x0 = xp[p], x1 = xp[p + 1], x2 = xp[p + 2];
        const f32x2 xv0 = {x0, x0}, xv1 = {x1, x1}, xv2 = {x2, x2};
        const f32x2 zero = {0.f, 0.f};
        unsigned int hp[8];
#pragma unroll
        for (int cp = 0; cp < 8; cp++) {
            f32x2 a = bb[cp];
            a = __builtin_elementwise_fma(wt0[cp], xv0, a);
            a = __builtin_elementwise_fma(wt1[cp], xv1, a);
            a = __builtin_elementwise_fma(wt2[cp], xv2, a);
            a = __builtin_elementwise_max(a, zero);
            hp[cp] = pack_bf16x2(a[0], a[1]);
        }
        uint2* d = (uint2*)&yh[(p + 1) * YPITCH];
        d[0] = make_uint2(hp[0], hp[1]);
        d[1] = make_uint2(hp[2], hp[3]);
        d[2] = make_uint2(hp[4], hp[5]);
        d[3] = make_uint2(hp[6], hp[7]);
    }
    __syncthreads();

    struct S8 { short4 lo, hi; };
    float mx0 = -3.0e38f, mx1 = -3.0e38f, mx2 = -3.0e38f, mx3 = -3.0e38f;
#pragma unroll
    for (int it = 0; it < 8; it++) {
        const int tile = wave * 8 + it;
        const int p0 = tile * 16 + n16;
        const int cA = (q & 1) * 8;
        const int rA = p0 + (q >> 1);
        const int rB = p0 + 2 + (q >> 1);
        S8 t0, t1;
        t0.lo = *(const short4*)&yh[rA * YPITCH + cA];
        t0.hi = *(const short4*)&yh[rA * YPITCH + cA + 4];
        t1.lo = *(const short4*)&yh[rB * YPITCH + cA];
        t1.hi = *(const short4*)&yh[rB * YPITCH + cA + 4];
        const s16x8 ah0 = *(const s16x8*)&t0;
        const s16x8 ah1 = *(const s16x8*)&t1;
        f32x4 acc = {0.f, 0.f, 0.f, 0.f};
        acc = __builtin_amdgcn_mfma_f32_16x16x32_bf16(ah0, bh0, acc, 0, 0, 0);
        acc = __builtin_amdgcn_mfma_f32_16x16x32_bf16(ah1, bh1, acc, 0, 0, 0);
        if (it < 7) {
            mx0 = fmaxf(mx0, acc[0]);
            mx1 = fmaxf(mx1, acc[1]);
            mx2 = fmaxf(mx2, acc[2]);
            mx3 = fmaxf(mx3, acc[3]);
        } else if (wave < 3) {
            mx0 = fmaxf(mx0, acc[0]);
            mx1 = fmaxf(mx1, acc[1]);
            mx2 = fmaxf(mx2, acc[2]);
            mx3 = fmaxf(mx3, acc[3]);
        } else if (q == 0) {
            mx0 = fmaxf(mx0, acc[0]);
            mx1 = fmaxf(mx1, acc[1]);
            mx2 = fmaxf(mx2, acc[2]);
            mx3 = fmaxf(mx3, acc[3]);
        }
    }
    float m = fmaxf(fmaxf(mx0, mx1), fmaxf(mx2, mx3));
    m = fmaxf(m, __shfl_xor(m, 16));
    m = fmaxf(m, __shfl_xor(m, 32));
    if (lane < 16) red[wave * 16 + lane] = m;
    __syncthreads();
    if (tid < 16) {
        const float mm = fmaxf(fmaxf(red[tid], red[16 + tid]), fmaxf(red[32 + tid], red[48 + tid]));
        h0[node * HID + tid] = fmaxf(mm + b2[tid], 0.f);
    }
}

// ---------------- K2: reorder (fused int2 scan) + dinv + h0 prescale ---------
__global__ __launch_bounds__(512) void reorder2(
    const int* __restrict__ src, const int* __restrict__ dst,
    const int* __restrict__ cntbase, int* __restrict__ packed,
    int* __restrict__ binstart, const int* __restrict__ degi,
    float* __restrict__ dinv, float* __restrict__ h0)
{
    __shared__ int2 sc2A[NBIN], sc2B[NBIN];
    __shared__ int gexc[NBIN];
    __shared__ int lexc[NBIN];
    __shared__ int cursor[NBIN];
    __shared__ int srt[EPRH];
    const int tid = threadIdx.x;
    const int blk = blockIdx.x;

    for (int bin = tid; bin < NBIN; bin += 512) {
        int tot = 0, psum = 0, lc = 0;
        for (int k = 0; k < HBLK; k++) {
            const int c = cntbase[k * NBIN + bin];
            tot += c;
            if (k < blk) psum += c;
            if (k == blk) lc = c;
        }
        cursor[bin] = tot;
        gexc[bin]   = psum;
        lexc[bin]   = lc;
        sc2A[bin]   = make_int2(tot, lc);
    }
    __syncthreads();
    {
        int2* pA = sc2A; int2* pB = sc2B;
        for (int off = 1; off < NBIN; off <<= 1) {
            for (int i = tid; i < NBIN; i += 512) {
                int2 v = pA[i];
                if (i >= off) { const int2 u = pA[i - off]; v.x += u.x; v.y += u.y; }
                pB[i] = v;
            }
            __syncthreads();
            int2* tp = pA; pA = pB; pB = tp;
        }
        for (int i = tid; i < NBIN; i += 512) {
            const int tot = cursor[i];
            const int lc  = lexc[i];
            const int et  = pA[i].x - tot;   // global binstart
            const int el  = pA[i].y - lc;    // local exclusive
            gexc[i] += et;
            if (blk == 0) binstart[i] = et;
            lexc[i]   = el;
            cursor[i] = el;
        }
        if (blk == 0 && tid == 0) binstart[NBIN] = NEDGE;
    }
    __syncthreads();
    const int e0 = blk * EPRH;
    for (int e = e0 + tid; e < e0 + EPRH; e += 512) {
        const int d = dst[e];
        const int bin = d >> 5;
        const int pos = atomicAdd(&cursor[bin], 1);
        srt[pos] = src[e] | (d << 15);
    }
    __syncthreads();
    for (int i = tid; i < EPRH; i += 512) {
        const int bin = srt[i] >> 20;
        packed[gexc[bin] + (i - lexc[bin])] = srt[i];
    }
    const int n0 = blk * NPB2;
    for (int n = n0 + tid; n < n0 + NPB2 && n < N_NODES; n += 512) {
        const float dv = rsqrtf((float)(degi[n] + 1));
        dinv[n] = dv;
        f32x4* h4 = (f32x4*)(h0 + n * HID);
#pragma unroll
        for (int k = 0; k < 4; k++) h4[k] = h4[k] * dv;
    }
}

// ---------------- K3: agg layer 1 + W1 + relu + W2; emits sorted packed ------
// t2p4[node] = (t2p.x, t2p.y, t2p.z, dv); binofs[blk*64+{0..31:start,32..63:count}]
__global__ __launch_bounds__(256) void agg1_kernel(
    const int* __restrict__ binstart, int* __restrict__ packed,
    const float* __restrict__ h0,
    const float* __restrict__ W1, const float* __restrict__ b1g,
    const float* __restrict__ W2, float4* __restrict__ t2p4,
    int* __restrict__ binofs)
{
    __shared__ float w1s[256];
    __shared__ float w2s[48];
    __shared__ float b1s[16];
    __shared__ float accS[32 * 17];
    __shared__ int eL[ECAP];
    __shared__ int srt[ECAP];
    __shared__ int h32[32], ls32[32], lofs32[32];
    const int tid = threadIdx.x;
    const int blk = blockIdx.x;
    w1s[tid] = W1[tid];
    if (tid < 48) w2s[tid] = W2[tid];
    if (tid < 16) b1s[tid] = b1g[tid];
    if (tid < 32) h32[tid] = 0;
    const int beg = binstart[blk];
    const int cnt = binstart[blk + 1] - beg;
    __syncthreads();
    for (int j = tid; j < cnt; j += 256) {
        const int p = packed[beg + j];
        eL[j] = p;
        atomicAdd(&h32[(p >> 15) & 31], 1);
    }
    __syncthreads();
    if (tid < 32) {
        const int v = h32[tid];
        int inc = v;
#pragma unroll
        for (int off = 1; off < 32; off <<= 1) {
            const int y = __shfl_up(inc, off);
            if (tid >= off) inc += y;
        }
        ls32[tid] = inc - v;
        lofs32[tid] = inc - v;
    }
    __syncthreads();
    for (int j = tid; j < cnt; j += 256) {
        const int p = eL[j];
        const int pos = atomicAdd(&lofs32[(p >> 15) & 31], 1);
        srt[pos] = p;
    }
    __syncthreads();
    // writeback sorted edges + per-node offsets for agg2 (coalesced)
    for (int j = tid; j < cnt; j += 256) packed[beg + j] = srt[j];
    if (tid < 32) {
        binofs[blk * 64 + tid]      = ls32[tid];
        binofs[blk * 64 + 32 + tid] = h32[tid];
    }
    const int n = tid >> 3;
    const int eslot = (tid >> 2) & 1;
    const int q = tid & 3;
    const int node = blk * 32 + n;
    const bool valid = node < N_NODES;
    f32x4 acc = {0.f, 0.f, 0.f, 0.f};
    if (valid) {
        const int s0 = ls32[n];
        const int s1 = s0 + h32[n];
        for (int i = s0 + eslot; i < s1; i += 2) {
            const int s = srt[i] & 32767;
            acc += *(const f32x4*)(h0 + s * HID + q * 4);
        }
    }
#pragma unroll
    for (int c = 0; c < 4; c++) acc[c] += __shfl_xor(acc[c], 4);
    if (valid && eslot == 0) {
        acc += *(const f32x4*)(h0 + node * HID + q * 4);   // self (prescaled)
        accS[n * 17 + q * 4 + 0] = acc[0];
        accS[n * 17 + q * 4 + 1] = acc[1];
        accS[n * 17 + q * 4 + 2] = acc[2];
        accS[n * 17 + q * 4 + 3] = acc[3];
    }
    __syncthreads();
    if (tid < 128) {
        const int n2 = tid >> 2;
        const int node2 = blk * 32 + n2;
        if (node2 < N_NODES) {
            const float dv = rsqrtf((float)(h32[n2] + 1));
            const int q2 = tid & 3;
            float y0 = 0.f, y1 = 0.f, y2 = 0.f, y3 = 0.f;
#pragma unroll
            for (int i = 0; i < 16; i++) {
                const float a = accS[n2 * 17 + i];
                y0 = fmaf(a, w1s[i * 16 + q2 * 4 + 0], y0);
                y1 = fmaf(a, w1s[i * 16 + q2 * 4 + 1], y1);
                y2 = fmaf(a, w1s[i * 16 + q2 * 4 + 2], y2);
                y3 = fmaf(a, w1s[i * 16 + q2 * 4 + 3], y3);
            }
            float d0 = 0.f, d1 = 0.f, d2 = 0.f;
            const float yv[4] = {y0, y1, y2, y3};
#pragma unroll
            for (int j = 0; j < 4; j++) {
                const int o = q2 * 4 + j;
                const float h = fmaxf(b1s[o] + dv * yv[j], 0.f);
                d0 = fmaf(h, w2s[o * 3 + 0], d0);
                d1 = fmaf(h, w2s[o * 3 + 1], d1);
                d2 = fmaf(h, w2s[o * 3 + 2], d2);
            }
            d0 += __shfl_xor(d0, 1); d0 += __shfl_xor(d0, 2);
            d1 += __shfl_xor(d1, 1); d1 += __shfl_xor(d1, 2);
            d2 += __shfl_xor(d2, 1); d2 += __shfl_xor(d2, 2);
            if (q2 == 0) t2p4[node2] = make_float4(d0 * dv, d1 * dv, d2 * dv, dv);
        }
    }
}

// ---------------- K4: agg layer 2 (pre-sorted, no atomics) + log_softmax -----
__global__ __launch_bounds__(256) void agg2_kernel(
    const int* __restrict__ binstart, const int* __restrict__ packed,
    const float4* __restrict__ t2p4, const int* __restrict__ binofs,
    const float* __restrict__ b2g, float* __restrict__ out)
{
    __shared__ int eL[ECAP];
    __shared__ int ofs[64];
    const int tid = threadIdx.x;
    const int blk = blockIdx.x;
    const int beg = binstart[blk];
    const int cnt = binstart[blk + 1] - beg;
    if (tid < 64) ofs[tid] = binofs[blk * 64 + tid];
    for (int j = tid; j < cnt; j += 256) eL[j] = packed[beg + j];
    __syncthreads();
    const int n = tid >> 3;
    const int ln8 = tid & 7;
    const int node = blk * 32 + n;
    float a0 = 0.f, a1 = 0.f, a2 = 0.f;
    if (node < N_NODES) {
        const int s0 = ofs[n];
        const int s1 = s0 + ofs[32 + n];
        for (int i = s0 + ln8; i < s1; i += 8) {
            const int s = eL[i] & 32767;
            const float4 v = t2p4[s];
            a0 += v.x; a1 += v.y; a2 += v.z;
        }
    }
#pragma unroll
    for (int msk = 1; msk < 8; msk <<= 1) {
        a0 += __shfl_xor(a0, msk);
        a1 += __shfl_xor(a1, msk);
        a2 += __shfl_xor(a2, msk);
    }
    if (ln8 == 0 && node < N_NODES) {
        const float4 self = t2p4[node];
        const float dv = self.w;
        const float z0 = b2g[0] + dv * (a0 + self.x);
        const float z1 = b2g[1] + dv * (a1 + self.y);
        const float z2 = b2g[2] + dv * (a2 + self.z);
        const float m = fmaxf(z0, fmaxf(z1, z2));
        const float lg = m + logf(expf(z0 - m) + expf(z1 - m) + expf(z2 - m));
        out[node * 3 + 0] = z0 - lg;
        out[node * 3 + 1] = z1 - lg;
        out[node * 3 + 2] = z2 - lg;
    }
}

extern "C" void kernel_launch(void* const* d_in, const int* in_sizes, int n_in,
                              void* d_out, int out_size, void* d_ws, size_t ws_size,
                              hipStream_t stream)
{
    const float* x   = (const float*)d_in[0];
    const float* w1  = (const float*)d_in[1];
    const float* b1  = (const float*)d_in[2];
    const float* w2  = (const float*)d_in[3];
    const float* b2  = (const float*)d_in[4];
    const float* g1w = (const float*)d_in[5];
    const float* g1b = (const float*)d_in[6];
    const float* g2w = (const float*)d_in[7];
    const float* g2b = (const float*)d_in[8];
    const int*   ei  = (const int*)d_in[9];
    const int* src = ei;
    const int* dst = ei + NEDGE;

    float* ws = (float*)d_ws;
    float*  h0      = ws;                       // 480000 f (prescaled in place)
    float*  dinv    = ws + 480000;              // 30000 f
    float4* t2p4    = (float4*)(ws + 510000);   // 30000 float4 (16B aligned)
    int*    degi    = (int*)(ws + 630000);      // 30000 i
    int*    cntbase = (int*)(ws + 660000);      // 128*938 = 120064 i (blk-major)
    int*    binstart= (int*)(ws + 780064);      // 939 (+pad)
    int*    packed  = (int*)(ws + 781024);      // 960000 i
    int*    binofs  = (int*)(ws + 1741024);     // 938*64 = 60032 i
    short*  bfragsG = (short*)(ws + 1801056);   // 1024 s
    float*  out     = (float*)d_out;

    hipMemsetAsync(degi, 0, N_NODES * sizeof(int), stream);
    setup_kernel<<<1, 64, 0, stream>>>(w2, bfragsG);
    conv_hist<<<HBLK + N_NODES, 256, 0, stream>>>(x, w1, b1, b2, bfragsG,
                                                  dst, degi, cntbase, h0);
    reorder2<<<HBLK, 512, 0, stream>>>(src, dst, cntbase, packed, binstart,
                                       degi, dinv, h0);
    agg1_kernel<<<NBIN, 256, 0, stream>>>(binstart, packed, h0,
                                          g1w, g1b, g2w, t2p4, binofs);
    agg2_kernel<<<NBIN, 256, 0, stream>>>(binstart, packed, t2p4, binofs, g2b, out);
}

// Round 15
// 223.450 us; speedup vs baseline: 1.0490x; 1.0272x over previous
//
#include <hip/hip_runtime.h>
#include <hip/hip_bf16.h>

#define N_NODES 30000
#define F_INLEN 500
#define HID 16
#define OUTC 3
#define NEDGE 960000
#define YPITCH 20               // shorts per row: 40B -> conflict-free, 8B aligned
#define NBIN 938                // bins of 32 nodes: 938*32 = 30016 >= 30000
#define HBLK 128                // hist blocks (K0) and reorder riders (K1)
#define EPRH (NEDGE / HBLK)     // 7500 edges per hist/reorder block
#define ECAP 1536               // per-bin edge capacity (mean 1024, max ~1180)

typedef float  f32x4 __attribute__((ext_vector_type(4)));
typedef float  f32x2 __attribute__((ext_vector_type(2)));
typedef short  s16x8 __attribute__((ext_vector_type(8)));

static __device__ __forceinline__ unsigned short f2bf(float f) {
    unsigned int u = __float_as_uint(f);
    unsigned int r = (u + 0x7fffu + ((u >> 16) & 1u)) >> 16;
    return (unsigned short)r;
}
static __device__ __forceinline__ unsigned int pack_bf16x2(float v0, float v1) {
#if __has_builtin(__builtin_amdgcn_cvt_pk_bf16_f32)
    typedef __bf16 bf16x2_t __attribute__((ext_vector_type(2)));
    union { bf16x2_t v; unsigned int u; } cv;
    cv.v = __builtin_amdgcn_cvt_pk_bf16_f32(v0, v1);
    return cv.u;
#else
    return __builtin_amdgcn_perm(__float_as_uint(v1), __float_as_uint(v0), 0x07060302);
#endif
}

// ---------------- K0: [0..127] bin hist + degi; [128] B-fragments ------------
__global__ __launch_bounds__(256) void hist_kernel(
    const float* __restrict__ w2, short* __restrict__ bfragsG,
    const int* __restrict__ dst, int* __restrict__ degi, int* __restrict__ cntbase)
{
    const int tid = threadIdx.x;
    if (blockIdx.x == HBLK) {   // bfrag block
        if (tid < 64) {
            const int n16 = tid & 15, q = tid >> 4;
#pragma unroll
            for (int j = 0; j < 8; j++) {
                {   // s = 0
                    const int c = q * 8 + j;
                    const int t = c >> 4, i = c & 15;
                    bfragsG[tid * 16 + j] = (short)f2bf(w2[n16 * 48 + i * 3 + t]);
                }
                {   // s = 1 (zero for c >= 48)
                    const int c = 32 + q * 8 + j;
                    short v = 0;
                    if (c < 48) { const int t = c >> 4, i = c & 15; v = (short)f2bf(w2[n16 * 48 + i * 3 + t]); }
                    bfragsG[tid * 16 + 8 + j] = v;
                }
            }
        }
        return;
    }
    __shared__ int histH[NBIN];
    for (int i = tid; i < NBIN; i += 256) histH[i] = 0;
    __syncthreads();
    const int e0 = blockIdx.x * EPRH;
    for (int e = e0 + tid; e < e0 + EPRH; e += 256) {
        const int d = dst[e];
        atomicAdd(&histH[d >> 5], 1);
        atomicAdd(&degi[d], 1);
    }
    __syncthreads();
    for (int i = tid; i < NBIN; i += 256) cntbase[blockIdx.x * NBIN + i] = histH[i];
}

// ---------------- K1: [blocks 0..127] reorder riders  [128..30127] conv ------
// Riders: per-bin scan of cntbase -> binstart; direct global scatter of edges.
// Conv: conv1->relu->conv2(MFMA)->relu->max, epilogue prescaled by rsqrt(deg+1).
__global__ __launch_bounds__(256, 7) void conv_reorder(
    const float* __restrict__ x,
    const float* __restrict__ w1, const float* __restrict__ b1,
    const float* __restrict__ b2, const short* __restrict__ bfragsG,
    const int* __restrict__ src, const int* __restrict__ dst,
    const int* __restrict__ degi, const int* __restrict__ cntbase,
    int* __restrict__ packed, int* __restrict__ binstart,
    float* __restrict__ h0)
{
    __shared__ __align__(16) float xp[502];
    __shared__ __align__(16) unsigned short yh[516 * YPITCH];
    __shared__ float red[64];

    const int tid = threadIdx.x;

    if (blockIdx.x < HBLK) {
        // ---- reorder rider: LDS aliased onto conv's arrays (disjoint paths) ----
        int* scA    = (int*)yh;                 // 938
        int* scB    = scA + NBIN;               // 938
        int* totb   = scB + NBIN;               // 938
        int* cursor = totb + NBIN;              // 938  (total 15008 B < 23040)
        const int blk = blockIdx.x;
        for (int bin = tid; bin < NBIN; bin += 256) {
            int tot = 0, psum = 0;
            for (int k = 0; k < HBLK; k++) {
                const int c = cntbase[k * NBIN + bin];
                tot += c;
                if (k < blk) psum += c;
            }
            scA[bin]    = tot;
            totb[bin]   = tot;
            cursor[bin] = psum;
        }
        __syncthreads();
        int* pA = scA; int* pB = scB;
        for (int off = 1; off < NBIN; off <<= 1) {
            for (int i = tid; i < NBIN; i += 256)
                pB[i] = pA[i] + ((i >= off) ? pA[i - off] : 0);
            __syncthreads();
            int* tp = pA; pA = pB; pB = tp;
        }
        for (int i = tid; i < NBIN; i += 256) {
            const int excl = pA[i] - totb[i];
            cursor[i] += excl;
            if (blk == 0) binstart[i] = excl;
        }
        if (blk == 0 && tid == 0) binstart[NBIN] = NEDGE;
        __syncthreads();
        const int e0 = blk * EPRH;
        for (int e = e0 + tid; e < e0 + EPRH; e += 256) {
            const int d = dst[e];
            const int pos = atomicAdd(&cursor[d >> 5], 1);
            packed[pos] = src[e] | (d << 15);
        }
        return;
    }

    const int node = blockIdx.x - HBLK;
    const int lane = tid & 63;
    const int wave = tid >> 6;
    const int n16  = lane & 15;
    const int q    = lane >> 4;

    if (tid == 0) { xp[0] = 0.f; xp[501] = 0.f; }
    if (tid < 125) {
        const float4 v = ((const float4*)(x + (long long)node * F_INLEN))[tid];
        xp[4 * tid + 1] = v.x; xp[4 * tid + 2] = v.y;
        xp[4 * tid + 3] = v.z; xp[4 * tid + 4] = v.w;
    }
    {
        const int ri = tid >> 4;
        const int row = (ri == 0) ? 0 : (500 + ri);
        yh[row * YPITCH + (tid & 15)] = 0;
    }
    const s16x8* bfp = (const s16x8*)(bfragsG + lane * 16);
    const s16x8 bh0 = bfp[0], bh1 = bfp[1];

    f32x2 wt0[8], wt1[8], wt2[8], bb[8];
#pragma unroll
    for (int cp = 0; cp < 8; cp++) {
        const int c0 = 2 * cp, c1 = 2 * cp + 1;
        wt0[cp] = (f32x2){w1[c0 * 3 + 0], w1[c1 * 3 + 0]};
        wt1[cp] = (f32x2){w1[c0 * 3 + 1], w1[c1 * 3 + 1]};
        wt2[cp] = (f32x2){w1[c0 * 3 + 2], w1[c1 * 3 + 2]};
        bb[cp]  = (f32x2){b1[c0], b1[c1]};
    }
    __syncthreads();

    for (int p = tid; p < 500; p += 256) {
        const float x0 = xp[p], x1 = xp[p + 1], x2 = xp[p + 2];
        const f32x2 xv0 = {x0, x0}, xv1 = {x1, x1}, xv2 = {x2, x2};
        const f32x2 zero = {0.f, 0.f};
        unsigned int hp[8];
#pragma unroll
        for (int cp = 0; cp < 8; cp++) {
            f32x2 a = bb[cp];
            a = __builtin_elementwise_fma(wt0[cp], xv0, a);
            a = __builtin_elementwise_fma(wt1[cp], xv1, a);
            a = __builtin_elementwise_fma(wt2[cp], xv2, a);
            a = __builtin_elementwise_max(a, zero);
            hp[cp] = pack_bf16x2(a[0], a[1]);
        }
        uint2* d = (uint2*)&yh[(p + 1) * YPITCH];
        d[0] = make_uint2(hp[0], hp[1]);
        d[1] = make_uint2(hp[2], hp[3]);
        d[2] = make_uint2(hp[4], hp[5]);
        d[3] = make_uint2(hp[6], hp[7]);
    }
    __syncthreads();

    struct S8 { short4 lo, hi; };
    float mx0 = -3.0e38f, mx1 = -3.0e38f, mx2 = -3.0e38f, mx3 = -3.0e38f;
#pragma unroll
    for (int it = 0; it < 8; it++) {
        const int tile = wave * 8 + it;
        const int p0 = tile * 16 + n16;
        const int cA = (q & 1) * 8;
        const int rA = p0 + (q >> 1);
        const int rB = p0 + 2 + (q >> 1);
        S8 t0, t1;
        t0.lo = *(const short4*)&yh[rA * YPITCH + cA];
        t0.hi = *(const short4*)&yh[rA * YPITCH + cA + 4];
        t1.lo = *(const short4*)&yh[rB * YPITCH + cA];
        t1.hi = *(const short4*)&yh[rB * YPITCH + cA + 4];
        const s16x8 ah0 = *(const s16x8*)&t0;
        const s16x8 ah1 = *(const s16x8*)&t1;
        f32x4 acc = {0.f, 0.f, 0.f, 0.f};
        acc = __builtin_amdgcn_mfma_f32_16x16x32_bf16(ah0, bh0, acc, 0, 0, 0);
        acc = __builtin_amdgcn_mfma_f32_16x16x32_bf16(ah1, bh1, acc, 0, 0, 0);
        if (it < 7) {
            mx0 = fmaxf(mx0, acc[0]);
            mx1 = fmaxf(mx1, acc[1]);
            mx2 = fmaxf(mx2, acc[2]);
            mx3 = fmaxf(mx3, acc[3]);
        } else if (wave < 3) {
            mx0 = fmaxf(mx0, acc[0]);
            mx1 = fmaxf(mx1, acc[1]);
            mx2 = fmaxf(mx2, acc[2]);
            mx3 = fmaxf(mx3, acc[3]);
        } else if (q == 0) {
            mx0 = fmaxf(mx0, acc[0]);
            mx1 = fmaxf(mx1, acc[1]);
            mx2 = fmaxf(mx2, acc[2]);
            mx3 = fmaxf(mx3, acc[3]);
        }
    }
    float m = fmaxf(fmaxf(mx0, mx1), fmaxf(mx2, mx3));
    m = fmaxf(m, __shfl_xor(m, 16));
    m = fmaxf(m, __shfl_xor(m, 32));
    if (lane < 16) red[wave * 16 + lane] = m;
    __syncthreads();
    if (tid < 16) {
        const float mm = fmaxf(fmaxf(red[tid], red[16 + tid]), fmaxf(red[32 + tid], red[48 + tid]));
        const float dv = rsqrtf((float)(degi[node] + 1));   // degi complete (K0)
        h0[node * HID + tid] = fmaxf(mm + b2[tid], 0.f) * dv;
    }
}

// ---------------- K2: agg layer 1 + W1 + relu + W2; emits sorted packed ------
// t2p4[node] = (t2p.x, t2p.y, t2p.z, dv); binofs[blk*64+{0..31:start,32..63:count}]
__global__ __launch_bounds__(256) void agg1_kernel(
    const int* __restrict__ binstart, int* __restrict__ packed,
    const float* __restrict__ h0,
    const float* __restrict__ W1, const float* __restrict__ b1g,
    const float* __restrict__ W2, float4* __restrict__ t2p4,
    int* __restrict__ binofs)
{
    __shared__ float w1s[256];
    __shared__ float w2s[48];
    __shared__ float b1s[16];
    __shared__ float accS[32 * 17];
    __shared__ int eL[ECAP];
    __shared__ int srt[ECAP];
    __shared__ int h32[32], ls32[32], lofs32[32];
    const int tid = threadIdx.x;
    const int blk = blockIdx.x;
    w1s[tid] = W1[tid];
    if (tid < 48) w2s[tid] = W2[tid];
    if (tid < 16) b1s[tid] = b1g[tid];
    if (tid < 32) h32[tid] = 0;
    const int beg = binstart[blk];
    const int cnt = binstart[blk + 1] - beg;
    __syncthreads();
    for (int j = tid; j < cnt; j += 256) {
        const int p = packed[beg + j];
        eL[j] = p;
        atomicAdd(&h32[(p >> 15) & 31], 1);
    }
    __syncthreads();
    if (tid < 32) {
        const int v = h32[tid];
        int inc = v;
#pragma unroll
        for (int off = 1; off < 32; off <<= 1) {
            const int y = __shfl_up(inc, off);
            if (tid >= off) inc += y;
        }
        ls32[tid] = inc - v;
        lofs32[tid] = inc - v;
    }
    __syncthreads();
    for (int j = tid; j < cnt; j += 256) {
        const int p = eL[j];
        const int pos = atomicAdd(&lofs32[(p >> 15) & 31], 1);
        srt[pos] = p;
    }
    __syncthreads();
    // writeback sorted edges + per-node offsets for agg2 (coalesced)
    for (int j = tid; j < cnt; j += 256) packed[beg + j] = srt[j];
    if (tid < 32) {
        binofs[blk * 64 + tid]      = ls32[tid];
        binofs[blk * 64 + 32 + tid] = h32[tid];
    }
    const int n = tid >> 3;
    const int eslot = (tid >> 2) & 1;
    const int q = tid & 3;
    const int node = blk * 32 + n;
    const bool valid = node < N_NODES;
    f32x4 acc = {0.f, 0.f, 0.f, 0.f};
    if (valid) {
        const int s0 = ls32[n];
        const int s1 = s0 + h32[n];
        for (int i = s0 + eslot; i < s1; i += 2) {
            const int s = srt[i] & 32767;
            acc += *(const f32x4*)(h0 + s * HID + q * 4);
        }
    }
#pragma unroll
    for (int c = 0; c < 4; c++) acc[c] += __shfl_xor(acc[c], 4);
    if (valid && eslot == 0) {
        acc += *(const f32x4*)(h0 + node * HID + q * 4);   // self (prescaled)
        accS[n * 17 + q * 4 + 0] = acc[0];
        accS[n * 17 + q * 4 + 1] = acc[1];
        accS[n * 17 + q * 4 + 2] = acc[2];
        accS[n * 17 + q * 4 + 3] = acc[3];
    }
    __syncthreads();
    if (tid < 128) {
        const int n2 = tid >> 2;
        const int node2 = blk * 32 + n2;
        if (node2 < N_NODES) {
            const float dv = rsqrtf((float)(h32[n2] + 1));
            const int q2 = tid & 3;
            float y0 = 0.f, y1 = 0.f, y2 = 0.f, y3 = 0.f;
#pragma unroll
            for (int i = 0; i < 16; i++) {
                const float a = accS[n2 * 17 + i];
                y0 = fmaf(a, w1s[i * 16 + q2 * 4 + 0], y0);
                y1 = fmaf(a, w1s[i * 16 + q2 * 4 + 1], y1);
                y2 = fmaf(a, w1s[i * 16 + q2 * 4 + 2], y2);
                y3 = fmaf(a, w1s[i * 16 + q2 * 4 + 3], y3);
            }
            float d0 = 0.f, d1 = 0.f, d2 = 0.f;
            const float yv[4] = {y0, y1, y2, y3};
#pragma unroll
            for (int j = 0; j < 4; j++) {
                const int o = q2 * 4 + j;
                const float h = fmaxf(b1s[o] + dv * yv[j], 0.f);
                d0 = fmaf(h, w2s[o * 3 + 0], d0);
                d1 = fmaf(h, w2s[o * 3 + 1], d1);
                d2 = fmaf(h, w2s[o * 3 + 2], d2);
            }
            d0 += __shfl_xor(d0, 1); d0 += __shfl_xor(d0, 2);
            d1 += __shfl_xor(d1, 1); d1 += __shfl_xor(d1, 2);
            d2 += __shfl_xor(d2, 1); d2 += __shfl_xor(d2, 2);
            if (q2 == 0) t2p4[node2] = make_float4(d0 * dv, d1 * dv, d2 * dv, dv);
        }
    }
}

// ---------------- K3: agg layer 2 (pre-sorted, no atomics) + log_softmax -----
__global__ __launch_bounds__(256) void agg2_kernel(
    const int* __restrict__ binstart, const int* __restrict__ packed,
    const float4* __restrict__ t2p4, const int* __restrict__ binofs,
    const float* __restrict__ b2g, float* __restrict__ out)
{
    __shared__ int eL[ECAP];
    __shared__ int ofs[64];
    const int tid = threadIdx.x;
    const int blk = blockIdx.x;
    const int beg = binstart[blk];
    const int cnt = binstart[blk + 1] - beg;
    if (tid < 64) ofs[tid] = binofs[blk * 64 + tid];
    for (int j = tid; j < cnt; j += 256) eL[j] = packed[beg + j];
    __syncthreads();
    const int n = tid >> 3;
    const int ln8 = tid & 7;
    const int node = blk * 32 + n;
    float a0 = 0.f, a1 = 0.f, a2 = 0.f;
    if (node < N_NODES) {
        const int s0 = ofs[n];
        const int s1 = s0 + ofs[32 + n];
        for (int i = s0 + ln8; i < s1; i += 8) {
            const int s = eL[i] & 32767;
            const float4 v = t2p4[s];
            a0 += v.x; a1 += v.y; a2 += v.z;
        }
    }
#pragma unroll
    for (int msk = 1; msk < 8; msk <<= 1) {
        a0 += __shfl_xor(a0, msk);
        a1 += __shfl_xor(a1, msk);
        a2 += __shfl_xor(a2, msk);
    }
    if (ln8 == 0 && node < N_NODES) {
        const float4 self = t2p4[node];
        const float dv = self.w;
        const float z0 = b2g[0] + dv * (a0 + self.x);
        const float z1 = b2g[1] + dv * (a1 + self.y);
        const float z2 = b2g[2] + dv * (a2 + self.z);
        const float m = fmaxf(z0, fmaxf(z1, z2));
        const float lg = m + logf(expf(z0 - m) + expf(z1 - m) + expf(z2 - m));
        out[node * 3 + 0] = z0 - lg;
        out[node * 3 + 1] = z1 - lg;
        out[node * 3 + 2] = z2 - lg;
    }
}

extern "C" void kernel_launch(void* const* d_in, const int* in_sizes, int n_in,
                              void* d_out, int out_size, void* d_ws, size_t ws_size,
                              hipStream_t stream)
{
    const float* x   = (const float*)d_in[0];
    const float* w1  = (const float*)d_in[1];
    const float* b1  = (const float*)d_in[2];
    const float* w2  = (const float*)d_in[3];
    const float* b2  = (const float*)d_in[4];
    const float* g1w = (const float*)d_in[5];
    const float* g1b = (const float*)d_in[6];
    const float* g2w = (const float*)d_in[7];
    const float* g2b = (const float*)d_in[8];
    const int*   ei  = (const int*)d_in[9];
    const int* src = ei;
    const int* dst = ei + NEDGE;

    float* ws = (float*)d_ws;
    float*  h0      = ws;                       // 480000 f (prescaled at write)
    float4* t2p4    = (float4*)(ws + 480000);   // 30000 float4 (16B aligned)
    int*    degi    = (int*)(ws + 600000);      // 30000 i
    int*    cntbase = (int*)(ws + 630000);      // 128*938 = 120064 i (blk-major)
    int*    binstart= (int*)(ws + 750064);      // 939 (+pad)
    int*    packed  = (int*)(ws + 751104);      // 960000 i
    int*    binofs  = (int*)(ws + 1711104);     // 938*64 = 60032 i
    short*  bfragsG = (short*)(ws + 1771136);   // 1024 s
    float*  out     = (float*)d_out;

    hipMemsetAsync(degi, 0, N_NODES * sizeof(int), stream);
    hist_kernel<<<HBLK + 1, 256, 0, stream>>>(w2, bfragsG, dst, degi, cntbase);
    conv_reorder<<<HBLK + N_NODES, 256, 0, stream>>>(x, w1, b1, b2, bfragsG,
                                                     src, dst, degi, cntbase,
                                                     packed, binstart, h0);
    agg1_kernel<<<NBIN, 256, 0, stream>>>(binstart, packed, h0,
                                          g1w, g1b, g2w, t2p4, binofs);
    agg2_kernel<<<NBIN, 256, 0, stream>>>(binstart, packed, t2p4, binofs, g2b, out);
}